// Round 1
// baseline (624.098 us; speedup 1.0000x reference)
//
#include <hip/hip_runtime.h>

#define NN 8192
#define SBS 512    // super-block (grid-level) size
#define NSB 16     // number of super-blocks
#define SUB 64     // sub-block solved by one wave
#define NSUB 8     // SBS / SUB

// d_ws layout (floats): c_partial[8][NN] | s_arr[NN]

__device__ __forceinline__ float bcast(float v, int l) {
    return __int_as_float(__builtin_amdgcn_readlane(__float_as_int(v), l));
}
__device__ __forceinline__ float sigm(float x) {
    // 1 / (1 + exp(-x)) = 1 / (1 + exp2(-x*log2e))
    return __builtin_amdgcn_rcpf(1.0f + __builtin_amdgcn_exp2f(x * -1.44269504088896f));
}

__global__ void init_kernel(float* cp) {
    int i = blockIdx.x * blockDim.x + threadIdx.x;
    if (i < 8 * NN) cp[i] = 0.0f;
}

__global__ void __launch_bounds__(512) solve_kernel(
    const float* __restrict__ W, const float* __restrict__ b,
    const float* __restrict__ x, float* __restrict__ cp,
    float* __restrict__ s_arr, float* __restrict__ out, int k)
{
    __shared__ float sacc[SBS];           // running pre-activations for this super-block
    __shared__ float ssv[SBS];            // solved s values
    __shared__ float sdiag[2][SUB * SUB]; // double-buffered 64x64 strict-upper micro-block
    const int tid = threadIdx.x;
    const int J0 = k * SBS;

    // starting pre-activation: b + sum of the 8 partial-row-chunk accumulators
    {
        float a = b[J0 + tid];
        #pragma unroll
        for (int r = 0; r < 8; ++r) a += cp[r * NN + J0 + tid];
        sacc[tid] = a;
    }
    // stage diag micro-block for m=0 (strict upper: row<col, else 0)
    for (int idx = tid; idx < SUB * SUB; idx += 512) {
        int row = idx >> 6, col = idx & 63;
        sdiag[0][idx] = (row < col) ? W[(size_t)(J0 + row) * NN + (J0 + col)] : 0.0f;
    }
    float xv0 = x[0], xv1 = x[1];
    __syncthreads();

    for (int m = 0; m < NSUB; ++m) {
        const int base = m * SUB;
        if (tid < 64) {
            // ---- wave 0: the sequential 64-step chain ----
            const int l = tid;
            float wcol[SUB];
            #pragma unroll
            for (int j = 0; j < SUB; ++j) wcol[j] = sdiag[m & 1][j * SUB + l];
            float acc = sacc[base + l];
            float smine = 0.0f;
            const bool first = (k == 0) && (m == 0);
            #pragma unroll
            for (int j = 0; j < SUB; ++j) {
                float pre = bcast(acc, j);
                float sj;
                if (j == 0)      sj = first ? xv0 : sigm(pre);
                else if (j == 1) sj = first ? xv1 : sigm(pre);
                else             sj = sigm(pre);
                acc += wcol[j] * sj;   // wcol[j]==0 for l<=j, so strict-lower only
                if (l == j) smine = sj;
            }
            ssv[base + l] = smine;
            s_arr[J0 + base + l] = smine;
        } else if (m + 1 < NSUB) {
            // ---- waves 1..7: prefetch next diag micro-block ----
            const int nb = J0 + (m + 1) * SUB;
            for (int idx = tid - 64; idx < SUB * SUB; idx += 448) {
                int row = idx >> 6, col = idx & 63;
                sdiag[(m + 1) & 1][idx] =
                    (row < col) ? W[(size_t)(nb + row) * NN + (nb + col)] : 0.0f;
            }
        }
        __syncthreads();
        // ---- right-looking intra-super-block update ----
        const int ntarg = SBS - (m + 1) * SUB;
        if (tid < ntarg) {
            const int cl = (m + 1) * SUB + tid;
            const float* wp = W + (size_t)(J0 + base) * NN + (J0 + cl);
            float a0 = 0.f, a1 = 0.f, a2 = 0.f, a3 = 0.f;
            #pragma unroll
            for (int i = 0; i < SUB; i += 4) {
                a0 += wp[(size_t)(i + 0) * NN] * ssv[base + i + 0];
                a1 += wp[(size_t)(i + 1) * NN] * ssv[base + i + 1];
                a2 += wp[(size_t)(i + 2) * NN] * ssv[base + i + 2];
                a3 += wp[(size_t)(i + 3) * NN] * ssv[base + i + 3];
            }
            sacc[cl] += (a0 + a1) + (a2 + a3);
        }
        __syncthreads();
    }
    if (k == NSB - 1 && tid == 0) out[0] = ssv[SBS - 1];
}

__global__ void __launch_bounds__(256) update_kernel(
    const float* __restrict__ W, const float* __restrict__ s_arr,
    float* __restrict__ cp, int k)
{
    // rows [k*SBS,(k+1)*SBS) split into 8 chunks of 64 (blockIdx.y);
    // cols (k+1)*SBS + blockIdx.x*256 + tid
    __shared__ float ssh[SUB];
    const int tid = threadIdx.x;
    const int rc = blockIdx.y;
    const int row0 = k * SBS + rc * SUB;
    const int col = (k + 1) * SBS + blockIdx.x * 256 + tid;
    if (tid < SUB) ssh[tid] = s_arr[row0 + tid];
    __syncthreads();
    const float* wp = W + (size_t)row0 * NN + col;
    float a0 = 0.f, a1 = 0.f, a2 = 0.f, a3 = 0.f;
    #pragma unroll
    for (int i = 0; i < SUB; i += 4) {
        a0 += wp[(size_t)(i + 0) * NN] * ssh[i + 0];
        a1 += wp[(size_t)(i + 1) * NN] * ssh[i + 1];
        a2 += wp[(size_t)(i + 2) * NN] * ssh[i + 2];
        a3 += wp[(size_t)(i + 3) * NN] * ssh[i + 3];
    }
    cp[rc * NN + col] += (a0 + a1) + (a2 + a3);
}

extern "C" void kernel_launch(void* const* d_in, const int* in_sizes, int n_in,
                              void* d_out, int out_size, void* d_ws, size_t ws_size,
                              hipStream_t stream) {
    const float* x = (const float*)d_in[0];
    const float* W = (const float*)d_in[1];
    const float* b = (const float*)d_in[2];
    float* out = (float*)d_out;
    float* cp = (float*)d_ws;        // 8*NN floats
    float* s_arr = cp + 8 * NN;      // NN floats

    init_kernel<<<dim3((8 * NN) / 256), dim3(256), 0, stream>>>(cp);
    for (int k = 0; k < NSB; ++k) {
        solve_kernel<<<dim3(1), dim3(512), 0, stream>>>(W, b, x, cp, s_arr, out, k);
        if (k < NSB - 1) {
            int M = NN - (k + 1) * SBS;
            update_kernel<<<dim3(M / 256, 8), dim3(256), 0, stream>>>(W, s_arr, cp, k);
        }
    }
}